// Round 5
// baseline (1006.316 us; speedup 1.0000x reference)
//
#include <hip/hip_runtime.h>

// ---------------------------------------------------------------------------
// Pruned multi-head attention. fp32 I/O, split-bf16 (hi+lo) MFMA compute.
// B=2, S=2048, D_MODEL=1024, H=16, d_k=64, keep=int(2048*0.9)=1843
//
// Round 5: GEMMs retiled 64x64 (grid 1024 = 4 blocks/CU, was 1) with register
// double-buffered K loop; attn_av block barriers removed (Pl is per-wave LDS;
// in-order DS + lgkmcnt fence); exp2 with log2e/8 folded into Q projection;
// mask folded into V rows; linv folded into av epilogue; rowsum/colsum/av get
// explicit 2-deep load pipelines.
// ---------------------------------------------------------------------------

typedef __attribute__((ext_vector_type(8))) short short8;   // 8 bf16 (4 VGPRs)
typedef __attribute__((ext_vector_type(4))) short short4v;  // 4 bf16
typedef __attribute__((ext_vector_type(4))) float f32x4;    // MFMA C/D frag

#define KEEP 1843

#if __has_builtin(__builtin_amdgcn_exp2f)
  #define PEXP(x) __builtin_amdgcn_exp2f(x)
  #define QSC 0.18033688011112042f   // log2(e)/8 -> scores in log2 units
#else
  #define PEXP(x) __expf(x)
  #define QSC 0.125f
#endif

static __device__ __forceinline__ float bf2f(unsigned short s) {
    union { unsigned u; float f; } v; v.u = ((unsigned)s) << 16; return v.f;
}
static __device__ __forceinline__ unsigned short f2bf(float f) {
    union { float f; unsigned u; } v; v.f = f;
    unsigned u = v.u;
    unsigned r = (u + 0x7FFFu + ((u >> 16) & 1u)) >> 16;   // RNE
    return (unsigned short)r;
}

#define MFMA(A, B, C) __builtin_amdgcn_mfma_f32_16x16x32_bf16(A, B, C, 0, 0, 0)

// fp32 array -> hi/lo bf16 arrays (x = hi + lo to ~2^-17 relative)
__global__ __launch_bounds__(256) void cvt_split(
    const float* __restrict__ in, unsigned short* __restrict__ hi,
    unsigned short* __restrict__ lo, int n4)
{
    int i = blockIdx.x * 256 + threadIdx.x;
    if (i >= n4) return;
    f32x4 x = ((const f32x4*)in)[i];
    short4v h, l;
#pragma unroll
    for (int j = 0; j < 4; j++) {
        unsigned short hv = f2bf(x[j]);
        h[j] = (short)hv;
        l[j] = (short)f2bf(x[j] - bf2f(hv));
    }
    ((short4v*)hi)[i] = h;
    ((short4v*)lo)[i] = l;
}

// C = (A[M,1024] @ W[1024,1024]^T + bias) * scale, split-bf16 3-term.
// 64x64 block tile, 4 waves (2x2), each wave 32x32. grid (16, 64).
// mode 0: out hi+lo head layout [((b*16+h)*2048+s)*64+d]
// mode 2: out hi-only V^T [((b*16+h)*64+d)*2048+s]
__global__ __launch_bounds__(256) void gemm_qkv(
    const short* __restrict__ Ah, const short* __restrict__ Al,
    const short* __restrict__ Wh, const short* __restrict__ Wl,
    const float* __restrict__ bias, float scale,
    unsigned short* __restrict__ out_hi, unsigned short* __restrict__ out_lo,
    int mode)
{
    int tid  = threadIdx.x;
    int w    = tid >> 6;
    int lane = tid & 63;
    int ln   = lane & 15;
    int quad = lane >> 4;
    int rowBase = blockIdx.y * 64 + (w & 1) * 32;
    int colBase = blockIdx.x * 64 + (w >> 1) * 32;

    f32x4 acc[2][2];
#pragma unroll
    for (int i = 0; i < 2; i++)
#pragma unroll
        for (int j = 0; j < 2; j++) acc[i][j] = (f32x4){0.f, 0.f, 0.f, 0.f};

    short8 ah[2][2], al[2][2], wh[2][2], wl[2][2];   // [buf][tile]
    auto loadAB = [&](int buf, int kk) {
#pragma unroll
        for (int t = 0; t < 2; t++) {
            size_t ao = (size_t)(rowBase + t*16 + ln) * 1024 + kk + quad*8;
            ah[buf][t] = *(const short8*)(Ah + ao);
            al[buf][t] = *(const short8*)(Al + ao);
            size_t wo = (size_t)(colBase + t*16 + ln) * 1024 + kk + quad*8;
            wh[buf][t] = *(const short8*)(Wh + wo);
            wl[buf][t] = *(const short8*)(Wl + wo);
        }
    };
    auto comp = [&](int buf) {
#pragma unroll
        for (int mt = 0; mt < 2; mt++)
#pragma unroll
            for (int nt = 0; nt < 2; nt++) {
                acc[mt][nt] = MFMA(ah[buf][mt], wh[buf][nt], acc[mt][nt]);
                acc[mt][nt] = MFMA(ah[buf][mt], wl[buf][nt], acc[mt][nt]);
                acc[mt][nt] = MFMA(al[buf][mt], wh[buf][nt], acc[mt][nt]);
            }
    };

    loadAB(0, 0);
    for (int kk = 0; kk < 1024; kk += 64) {
        loadAB(1, kk + 32);
        comp(0);
        if (kk + 64 < 1024) loadAB(0, kk + 64);
        comp(1);
    }

#pragma unroll
    for (int mt = 0; mt < 2; mt++) {
#pragma unroll
        for (int nt = 0; nt < 2; nt++) {
            int col = colBase + nt*16 + ln;
            float bv = bias[col];
#pragma unroll
            for (int i = 0; i < 4; i++) {
                int row = rowBase + mt*16 + quad*4 + i;   // D: row=quad*4+reg, col=ln
                float val = (acc[mt][nt][i] + bv) * scale;
                int b_  = row >> 11, s = row & 2047;
                int h   = col >> 6,  d = col & 63;
                int bh_ = b_ * 16 + h;
                if (mode == 2) {
                    out_hi[((size_t)bh_ * 64 + d) * 2048 + s] = f2bf(val);
                } else {
                    size_t idx = ((size_t)bh_ * 2048 + s) * 64 + d;
                    unsigned short hv = f2bf(val);
                    out_hi[idx] = hv;
                    out_lo[idx] = f2bf(val - bf2f(hv));
                }
            }
        }
    }
}

// out[row,col] = sum_k concat_bf16[row,k] * Wo[col,k] + bo[col]  (split Wo, fp32 out)
__global__ __launch_bounds__(256) void gemm_out(
    const short* __restrict__ A,
    const short* __restrict__ Wh, const short* __restrict__ Wl,
    const float* __restrict__ bias, float* __restrict__ out)
{
    int tid  = threadIdx.x;
    int w    = tid >> 6;
    int lane = tid & 63;
    int ln   = lane & 15;
    int quad = lane >> 4;
    int rowBase = blockIdx.y * 64 + (w & 1) * 32;
    int colBase = blockIdx.x * 64 + (w >> 1) * 32;

    f32x4 acc[2][2];
#pragma unroll
    for (int i = 0; i < 2; i++)
#pragma unroll
        for (int j = 0; j < 2; j++) acc[i][j] = (f32x4){0.f, 0.f, 0.f, 0.f};

    short8 a[2][2], wh[2][2], wl[2][2];
    auto loadAB = [&](int buf, int kk) {
#pragma unroll
        for (int t = 0; t < 2; t++) {
            a[buf][t] = *(const short8*)(A + (size_t)(rowBase + t*16 + ln) * 1024 + kk + quad*8);
            size_t wo = (size_t)(colBase + t*16 + ln) * 1024 + kk + quad*8;
            wh[buf][t] = *(const short8*)(Wh + wo);
            wl[buf][t] = *(const short8*)(Wl + wo);
        }
    };
    auto comp = [&](int buf) {
#pragma unroll
        for (int mt = 0; mt < 2; mt++)
#pragma unroll
            for (int nt = 0; nt < 2; nt++) {
                acc[mt][nt] = MFMA(a[buf][mt], wh[buf][nt], acc[mt][nt]);
                acc[mt][nt] = MFMA(a[buf][mt], wl[buf][nt], acc[mt][nt]);
            }
    };

    loadAB(0, 0);
    for (int kk = 0; kk < 1024; kk += 64) {
        loadAB(1, kk + 32);
        comp(0);
        if (kk + 64 < 1024) loadAB(0, kk + 64);
        comp(1);
    }

#pragma unroll
    for (int mt = 0; mt < 2; mt++) {
#pragma unroll
        for (int nt = 0; nt < 2; nt++) {
            int col = colBase + nt*16 + ln;
            float bv = bias[col];
#pragma unroll
            for (int i = 0; i < 4; i++) {
                int row = rowBase + mt*16 + quad*4 + i;
                out[(size_t)row * 1024 + col] = acc[mt][nt][i] + bv;
            }
        }
    }
}

// linv[q] = 1 / sum_k 2^(c_qk)   (Q pre-scaled by log2e/8; no max shift)
// wave owns 32 q rows; grid (16,32); K double-buffered in registers.
__global__ __launch_bounds__(256) void attn_rowsum(
    const short* __restrict__ Qhi, const short* __restrict__ Qlo,
    const short* __restrict__ Khi, const short* __restrict__ Klo,
    float* __restrict__ linv_out)
{
    int bh = blockIdx.y, tid = threadIdx.x;
    int w = tid >> 6, lane = tid & 63, ln = lane & 15, quad = lane >> 4;
    int qb = blockIdx.x * 128 + w * 32;
    const short* QH = Qhi + (size_t)bh * 2048 * 64;
    const short* QL = Qlo + (size_t)bh * 2048 * 64;
    const short* KH = Khi + (size_t)bh * 2048 * 64;
    const short* KL = Klo + (size_t)bh * 2048 * 64;

    short8 qh[2][2], ql[2][2];
#pragma unroll
    for (int mt = 0; mt < 2; mt++)
#pragma unroll
        for (int half = 0; half < 2; half++) {
            size_t o = (size_t)(qb + mt*16 + ln) * 64 + half*32 + quad*8;
            qh[mt][half] = *(const short8*)(QH + o);
            ql[mt][half] = *(const short8*)(QL + o);
        }

    short8 kh[2][2], kl[2][2];   // [buf][half]
    auto loadK = [&](int buf, int kt) {
        size_t ko = (size_t)(kt*16 + ln) * 64 + quad*8;
        kh[buf][0] = *(const short8*)(KH + ko);
        kh[buf][1] = *(const short8*)(KH + ko + 32);
        kl[buf][0] = *(const short8*)(KL + ko);
        kl[buf][1] = *(const short8*)(KL + ko + 32);
    };

    float racc[2][4] = {{0.f,0.f,0.f,0.f},{0.f,0.f,0.f,0.f}};
    auto comp = [&](int buf) {
#pragma unroll
        for (int mt = 0; mt < 2; mt++) {
            f32x4 c1 = (f32x4){0.f,0.f,0.f,0.f};
            f32x4 c2 = (f32x4){0.f,0.f,0.f,0.f};
            c1 = MFMA(qh[mt][0], kh[buf][0], c1); c1 = MFMA(qh[mt][1], kh[buf][1], c1);
            c2 = MFMA(qh[mt][0], kl[buf][0], c2); c2 = MFMA(qh[mt][1], kl[buf][1], c2);
            c2 = MFMA(ql[mt][0], kh[buf][0], c2); c2 = MFMA(ql[mt][1], kh[buf][1], c2);
#pragma unroll
            for (int i = 0; i < 4; i++)
                racc[mt][i] += PEXP(c1[i] + c2[i]);
        }
    };

    loadK(0, 0);
    for (int kt = 0; kt < 128; kt += 2) {
        loadK(1, kt + 1);
        comp(0);
        if (kt + 2 < 128) loadK(0, kt + 2);
        comp(1);
    }
#pragma unroll
    for (int mt = 0; mt < 2; mt++)
#pragma unroll
        for (int i = 0; i < 4; i++)
            for (int d = 1; d < 16; d <<= 1)
                racc[mt][i] += __shfl_xor(racc[mt][i], d, 64);
    if (ln == 0) {
#pragma unroll
        for (int mt = 0; mt < 2; mt++)
#pragma unroll
            for (int i = 0; i < 4; i++)
                linv_out[bh * 2048 + qb + mt*16 + quad*4 + i] = 1.0f / racc[mt][i];
    }
}

// colsum[k] = sum_q 2^(c_qk) * linv[q].  Wave owns 32 keys; Q double-buffered.
__global__ __launch_bounds__(256) void attn_colsum(
    const short* __restrict__ Qhi, const short* __restrict__ Qlo,
    const short* __restrict__ Khi, const short* __restrict__ Klo,
    const float* __restrict__ linv, float* __restrict__ colsum)
{
    __shared__ float sli[2048];
    int bh = blockIdx.y, tid = threadIdx.x;
    for (int j = tid; j < 2048; j += 256) sli[j] = linv[bh * 2048 + j];
    __syncthreads();

    int w = tid >> 6, lane = tid & 63, ln = lane & 15, quad = lane >> 4;
    int kb = blockIdx.x * 128 + w * 32;
    const short* QH = Qhi + (size_t)bh * 2048 * 64;
    const short* QL = Qlo + (size_t)bh * 2048 * 64;
    const short* KH = Khi + (size_t)bh * 2048 * 64;
    const short* KL = Klo + (size_t)bh * 2048 * 64;

    short8 kh[2][2], kl[2][2];
#pragma unroll
    for (int nt = 0; nt < 2; nt++)
#pragma unroll
        for (int half = 0; half < 2; half++) {
            size_t o = (size_t)(kb + nt*16 + ln) * 64 + half*32 + quad*8;
            kh[nt][half] = *(const short8*)(KH + o);
            kl[nt][half] = *(const short8*)(KL + o);
        }

    short8 qh[2][2], ql[2][2];   // [buf][half]
    auto loadQ = [&](int buf, int qt) {
        size_t qo = (size_t)(qt*16 + ln) * 64 + quad*8;
        qh[buf][0] = *(const short8*)(QH + qo);
        qh[buf][1] = *(const short8*)(QH + qo + 32);
        ql[buf][0] = *(const short8*)(QL + qo);
        ql[buf][1] = *(const short8*)(QL + qo + 32);
    };

    float cacc[2] = {0.f, 0.f};
    auto comp = [&](int buf, int qt) {
#pragma unroll
        for (int nt = 0; nt < 2; nt++) {
            f32x4 c1 = (f32x4){0.f,0.f,0.f,0.f};
            f32x4 c2 = (f32x4){0.f,0.f,0.f,0.f};
            c1 = MFMA(qh[buf][0], kh[nt][0], c1); c1 = MFMA(qh[buf][1], kh[nt][1], c1);
            c2 = MFMA(qh[buf][0], kl[nt][0], c2); c2 = MFMA(qh[buf][1], kl[nt][1], c2);
            c2 = MFMA(ql[buf][0], kh[nt][0], c2); c2 = MFMA(ql[buf][1], kh[nt][1], c2);
#pragma unroll
            for (int i = 0; i < 4; i++) {
                int r = qt*16 + quad*4 + i;
                cacc[nt] += PEXP(c1[i] + c2[i]) * sli[r];
            }
        }
    };

    loadQ(0, 0);
    for (int qt = 0; qt < 128; qt += 2) {
        loadQ(1, qt + 1);
        comp(0, qt);
        if (qt + 2 < 128) loadQ(0, qt + 2);
        comp(1, qt + 1);
    }
#pragma unroll
    for (int nt = 0; nt < 2; nt++) {
        cacc[nt] += __shfl_xor(cacc[nt], 16, 64);
        cacc[nt] += __shfl_xor(cacc[nt], 32, 64);
        if (lane < 16) colsum[bh * 2048 + kb + nt*16 + lane] = cacc[nt];
    }
}

// Per (b,h): threshold = KEEP-th largest col_sum; mask = col_sum >= threshold.
__global__ __launch_bounds__(256) void topk_mask(
    const float* __restrict__ colsum, float* __restrict__ maskf)
{
    __shared__ unsigned keys[2048];
    __shared__ int cnt;
    int bh = blockIdx.x, tid = threadIdx.x;
    for (int j = tid; j < 2048; j += 256) {
        unsigned u = __float_as_uint(colsum[bh * 2048 + j]);
        keys[j] = (u & 0x80000000u) ? ~u : (u | 0x80000000u);  // order-preserving
    }
    __syncthreads();
    unsigned long long lo = 0, hi = 0x100000000ULL;
    while (hi - lo > 1) {
        unsigned long long mid = (lo + hi) >> 1;
        if (tid == 0) cnt = 0;
        __syncthreads();
        int local = 0;
        for (int j = tid; j < 2048; j += 256) local += (keys[j] >= (unsigned)mid) ? 1 : 0;
        atomicAdd(&cnt, local);
        __syncthreads();
        int c = cnt;
        __syncthreads();
        if (c >= KEEP) lo = mid; else hi = mid;
    }
    unsigned thr = (unsigned)lo;
    for (int j = tid; j < 2048; j += 256)
        maskf[bh * 2048 + j] = (keys[j] >= thr) ? 1.0f : 0.0f;
}

// Vt[(bh*64+d)*2048+k] *= mask[bh*2048+k]   (in place; mask is 0/1 -> exact)
__global__ __launch_bounds__(256) void mask_v(
    unsigned short* __restrict__ Vt, const float* __restrict__ maskf)
{
    int i = blockIdx.x * 256 + threadIdx.x;   // group of 8 keys
    int k8  = i & 255;
    int row = i >> 8;          // bh*64 + d
    int bh  = row >> 6;
    const float* m = maskf + bh * 2048 + k8 * 8;
    short8 v = ((short8*)Vt)[i];
#pragma unroll
    for (int j = 0; j < 8; j++)
        if (m[j] == 0.0f) v[j] = 0;
    ((short8*)Vt)[i] = v;
}

// Flash-style PV, no block barriers: Pl is per-wave LDS (in-order DS + fences).
// P = 2^c unnormalized; linv applied in epilogue. V pre-masked.
__global__ __launch_bounds__(256) void attn_av(
    const short* __restrict__ Qhi, const short* __restrict__ Khi,
    const short* __restrict__ Vt, const float* __restrict__ linv,
    unsigned short* __restrict__ concat)
{
    __shared__ __align__(16) short Pl[4][2][16][40];   // [wave][mt][row][key+pad]
    int bh = blockIdx.y, tid = threadIdx.x;
    int w = tid >> 6, lane = tid & 63, ln = lane & 15, quad = lane >> 4;
    int qb = blockIdx.x * 128 + w * 32;
    const short* Q = Qhi + (size_t)bh * 2048 * 64;
    const short* K = Khi + (size_t)bh * 2048 * 64;
    const short* V = Vt  + (size_t)bh * 64 * 2048;

    short8 qh[2][2];
    float lrow[2][4];
#pragma unroll
    for (int mt = 0; mt < 2; mt++) {
#pragma unroll
        for (int half = 0; half < 2; half++)
            qh[mt][half] = *(const short8*)(Q + (size_t)(qb + mt*16 + ln) * 64 + half*32 + quad*8);
#pragma unroll
        for (int i = 0; i < 4; i++)
            lrow[mt][i] = linv[bh * 2048 + qb + mt*16 + quad*4 + i];
    }

    f32x4 o[2][4];
#pragma unroll
    for (int mt = 0; mt < 2; mt++)
#pragma unroll
        for (int nt = 0; nt < 4; nt++) o[mt][nt] = (f32x4){0.f,0.f,0.f,0.f};

    short8 kb_[2][2][2];   // [buf][half][part]
    short8 vb_[2][4];      // [buf][nt]
    auto loadKV = [&](int buf, int kc) {
#pragma unroll
        for (int half = 0; half < 2; half++) {
            size_t ko = (size_t)(kc*32 + half*16 + ln) * 64 + quad*8;
            kb_[buf][half][0] = *(const short8*)(K + ko);
            kb_[buf][half][1] = *(const short8*)(K + ko + 32);
        }
#pragma unroll
        for (int nt = 0; nt < 4; nt++)
            vb_[buf][nt] = *(const short8*)(V + (size_t)(nt*16 + ln) * 2048 + kc*32 + quad*8);
    };
    auto comp = [&](int buf) {
#pragma unroll
        for (int half = 0; half < 2; half++)
#pragma unroll
            for (int mt = 0; mt < 2; mt++) {
                f32x4 c = (f32x4){0.f,0.f,0.f,0.f};
                c = MFMA(qh[mt][0], kb_[buf][half][0], c);
                c = MFMA(qh[mt][1], kb_[buf][half][1], c);
#pragma unroll
                for (int i = 0; i < 4; i++)
                    Pl[w][mt][quad*4 + i][half*16 + ln] = (short)f2bf(PEXP(c[i]));
            }
        asm volatile("s_waitcnt lgkmcnt(0)" ::: "memory");   // P writes visible to wave
        short8 aP[2];
#pragma unroll
        for (int mt = 0; mt < 2; mt++)
            aP[mt] = *(const short8*)(&Pl[w][mt][ln][quad*8]);
#pragma unroll
        for (int nt = 0; nt < 4; nt++)
#pragma unroll
            for (int mt = 0; mt < 2; mt++)
                o[mt][nt] = MFMA(aP[mt], vb_[buf][nt], o[mt][nt]);
        asm volatile("" ::: "memory");   // keep next writes after these reads
    };

    loadKV(0, 0);
    for (int kc = 0; kc < 64; kc += 2) {
        loadKV(1, kc + 1);
        comp(0);
        if (kc + 2 < 64) loadKV(0, kc + 2);
        comp(1);
    }

    int b_ = bh >> 4, h = bh & 15;
#pragma unroll
    for (int mt = 0; mt < 2; mt++)
#pragma unroll
        for (int nt = 0; nt < 4; nt++)
#pragma unroll
            for (int i = 0; i < 4; i++) {
                int qrow = qb + mt*16 + quad*4 + i;
                int col  = h*64 + nt*16 + ln;
                concat[((size_t)(b_*2048 + qrow)) * 1024 + col] =
                    f2bf(o[mt][nt][i] * lrow[mt][i]);
            }
}

extern "C" void kernel_launch(void* const* d_in, const int* in_sizes, int n_in,
                              void* d_out, int out_size, void* d_ws, size_t ws_size,
                              hipStream_t stream)
{
    const float* q  = (const float*)d_in[0];
    const float* k  = (const float*)d_in[1];
    const float* v  = (const float*)d_in[2];
    const float* Wq = (const float*)d_in[3];
    const float* bq = (const float*)d_in[4];
    const float* Wk = (const float*)d_in[5];
    const float* bk = (const float*)d_in[6];
    const float* Wv = (const float*)d_in[7];
    const float* bv = (const float*)d_in[8];
    const float* Wo = (const float*)d_in[9];
    const float* bo = (const float*)d_in[10];

    char* ws = (char*)d_ws;
    size_t off = 0;
    auto alloc = [&](size_t bytes) -> void* {
        void* p = ws + off;
        off += (bytes + 255) & ~(size_t)255;
        return p;
    };
    const size_t ASZ = (size_t)4096 * 1024 * 2;
    const size_t WSZ = (size_t)1024 * 1024 * 2;
    unsigned short* qh_ = (unsigned short*)alloc(ASZ);
    unsigned short* ql_ = (unsigned short*)alloc(ASZ);
    unsigned short* kh_ = (unsigned short*)alloc(ASZ);
    unsigned short* kl_ = (unsigned short*)alloc(ASZ);
    unsigned short* vh_ = (unsigned short*)alloc(ASZ);
    unsigned short* vl_ = (unsigned short*)alloc(ASZ);
    unsigned short* wqh = (unsigned short*)alloc(WSZ);
    unsigned short* wql = (unsigned short*)alloc(WSZ);
    unsigned short* wkh = (unsigned short*)alloc(WSZ);
    unsigned short* wkl = (unsigned short*)alloc(WSZ);
    unsigned short* wvh = (unsigned short*)alloc(WSZ);
    unsigned short* wvl = (unsigned short*)alloc(WSZ);
    unsigned short* woh = (unsigned short*)alloc(WSZ);
    unsigned short* wol = (unsigned short*)alloc(WSZ);
    short* Qhi = (short*)alloc(ASZ);
    short* Qlo = (short*)alloc(ASZ);
    short* Khi = (short*)alloc(ASZ);
    short* Klo = (short*)alloc(ASZ);
    short* Vt  = (short*)alloc(ASZ);
    float* lrow   = (float*)alloc((size_t)32 * 2048 * 4);
    float* colsum = (float*)alloc((size_t)32 * 2048 * 4);
    float* maskf  = (float*)alloc((size_t)32 * 2048 * 4);
    unsigned short* concat = (unsigned short*)alloc(ASZ);

    dim3 blk(256);
    const int An4 = 4096 * 1024 / 4, Wn4 = 1024 * 1024 / 4;

    cvt_split<<<An4/256, blk, 0, stream>>>(q,  qh_, ql_, An4);
    cvt_split<<<An4/256, blk, 0, stream>>>(k,  kh_, kl_, An4);
    cvt_split<<<An4/256, blk, 0, stream>>>(v,  vh_, vl_, An4);
    cvt_split<<<Wn4/256, blk, 0, stream>>>(Wq, wqh, wql, Wn4);
    cvt_split<<<Wn4/256, blk, 0, stream>>>(Wk, wkh, wkl, Wn4);
    cvt_split<<<Wn4/256, blk, 0, stream>>>(Wv, wvh, wvl, Wn4);
    cvt_split<<<Wn4/256, blk, 0, stream>>>(Wo, woh, wol, Wn4);

    dim3 gemm_grid(16, 64);   // N/64, M/64
    gemm_qkv<<<gemm_grid, blk, 0, stream>>>((const short*)qh_, (const short*)ql_,
        (const short*)wqh, (const short*)wql, bq, QSC,
        (unsigned short*)Qhi, (unsigned short*)Qlo, 0);
    gemm_qkv<<<gemm_grid, blk, 0, stream>>>((const short*)kh_, (const short*)kl_,
        (const short*)wkh, (const short*)wkl, bk, 1.0f,
        (unsigned short*)Khi, (unsigned short*)Klo, 0);
    gemm_qkv<<<gemm_grid, blk, 0, stream>>>((const short*)vh_, (const short*)vl_,
        (const short*)wvh, (const short*)wvl, bv, 1.0f,
        (unsigned short*)Vt, (unsigned short*)Vt, 2);

    attn_rowsum<<<dim3(16, 32), blk, 0, stream>>>(Qhi, Qlo, Khi, Klo, lrow);
    attn_colsum<<<dim3(16, 32), blk, 0, stream>>>(Qhi, Qlo, Khi, Klo, lrow, colsum);
    topk_mask  <<<dim3(32),     blk, 0, stream>>>(colsum, maskf);
    mask_v     <<<dim3(2048),   blk, 0, stream>>>((unsigned short*)Vt, maskf);
    attn_av    <<<dim3(16, 32), blk, 0, stream>>>(Qhi, Khi, Vt, lrow, concat);

    gemm_out<<<gemm_grid, blk, 0, stream>>>((const short*)concat,
        (const short*)woh, (const short*)wol, bo, (float*)d_out);
}

// Round 7
// 848.856 us; speedup vs baseline: 1.1855x; 1.1855x over previous
//
#include <hip/hip_runtime.h>

// ---------------------------------------------------------------------------
// Pruned multi-head attention. fp32 I/O, split-bf16 (hi+lo) MFMA compute.
// B=2, S=2048, D_MODEL=1024, H=16, d_k=64, keep=int(2048*0.9)=1843
//
// Round 7 (R6 crashed: 268MB P buffer overflowed ws — stay ~118MB):
//  - gemm_qkv fused via blockIdx.z (768 blocks = 3/CU), 128x128 body
//  - rowsum k-split x2, colsum q-split x2 (1024 blocks = 4/CU), fp32 atomics
//  - linv deleted: 1/rowsum computed inline at use sites
//  - attn_av: R5 no-block-barrier version (per-wave LDS P roundtrip)
// ---------------------------------------------------------------------------

typedef __attribute__((ext_vector_type(8))) short short8;   // 8 bf16 (4 VGPRs)
typedef __attribute__((ext_vector_type(4))) short short4v;
typedef __attribute__((ext_vector_type(4))) float f32x4;

#define KEEP 1843

#if __has_builtin(__builtin_amdgcn_exp2f)
  #define PEXP(x) __builtin_amdgcn_exp2f(x)
  #define QSC 0.18033688011112042f   // log2(e)/8 folded into Q projection
#else
  #define PEXP(x) __expf(x)
  #define QSC 0.125f
#endif

static __device__ __forceinline__ float bf2f(unsigned short s) {
    union { unsigned u; float f; } v; v.u = ((unsigned)s) << 16; return v.f;
}
static __device__ __forceinline__ unsigned short f2bf(float f) {
    union { float f; unsigned u; } v; v.f = f;
    unsigned u = v.u;
    unsigned r = (u + 0x7FFFu + ((u >> 16) & 1u)) >> 16;   // RNE
    return (unsigned short)r;
}

#define MFMA(A, B, C) __builtin_amdgcn_mfma_f32_16x16x32_bf16(A, B, C, 0, 0, 0)

// fp32 array -> hi/lo bf16 arrays (x = hi + lo to ~2^-17 relative)
__global__ __launch_bounds__(256) void cvt_split(
    const float* __restrict__ in, unsigned short* __restrict__ hi,
    unsigned short* __restrict__ lo, int n4)
{
    int i = blockIdx.x * 256 + threadIdx.x;
    if (i >= n4) return;
    f32x4 x = ((const f32x4*)in)[i];
    short4v h, l;
#pragma unroll
    for (int j = 0; j < 4; j++) {
        unsigned short hv = f2bf(x[j]);
        h[j] = (short)hv;
        l[j] = (short)f2bf(x[j] - bf2f(hv));
    }
    ((short4v*)hi)[i] = h;
    ((short4v*)lo)[i] = l;
}

__global__ __launch_bounds__(256) void zero_f32(float* __restrict__ p, int n) {
    int i = blockIdx.x * 256 + threadIdx.x;
    if (i < n) p[i] = 0.f;
}

// Fused Q/K/V projections: z = blockIdx.z. 128x128 tile, split-bf16 3-term.
// z=0: Q -> bf16 hi+lo head layout, scaled by QSC
// z=1: K -> bf16 hi+lo head layout
// z=2: V -> bf16 V^T [((b*16+h)*64+d)*2048+s]
__global__ __launch_bounds__(256) void gemm_qkv(
    const short* __restrict__ A0, const short* __restrict__ Al0,
    const short* __restrict__ A1, const short* __restrict__ Al1,
    const short* __restrict__ A2, const short* __restrict__ Al2,
    const short* __restrict__ W0, const short* __restrict__ Wl0,
    const short* __restrict__ W1, const short* __restrict__ Wl1,
    const short* __restrict__ W2, const short* __restrict__ Wl2,
    const float* __restrict__ b0, const float* __restrict__ b1,
    const float* __restrict__ b2,
    unsigned short* __restrict__ Qhi, unsigned short* __restrict__ Qlo,
    unsigned short* __restrict__ Khi, unsigned short* __restrict__ Klo,
    unsigned short* __restrict__ Vt)
{
    int z = blockIdx.z;
    const short *Ah, *Al, *Wh, *Wl; const float* bias;
    unsigned short *oh = 0, *ol = 0; float scale; int mode;
    if (z == 0)      { Ah=A0; Al=Al0; Wh=W0; Wl=Wl0; bias=b0; oh=Qhi; ol=Qlo; scale=QSC;  mode=0; }
    else if (z == 1) { Ah=A1; Al=Al1; Wh=W1; Wl=Wl1; bias=b1; oh=Khi; ol=Klo; scale=1.0f; mode=0; }
    else             { Ah=A2; Al=Al2; Wh=W2; Wl=Wl2; bias=b2; oh=Vt;          scale=1.0f; mode=2; }

    int tid  = threadIdx.x;
    int w    = tid >> 6;
    int lane = tid & 63;
    int ln   = lane & 15;
    int quad = lane >> 4;
    int rowBase = blockIdx.y * 128 + (w & 1) * 64;
    int colBase = blockIdx.x * 128 + (w >> 1) * 64;

    f32x4 acc[4][4];
#pragma unroll
    for (int i = 0; i < 4; i++)
#pragma unroll
        for (int j = 0; j < 4; j++) acc[i][j] = (f32x4){0.f, 0.f, 0.f, 0.f};

    for (int kk = 0; kk < 1024; kk += 32) {
        short8 ah[4], al[4], bh[4], bl[4];
#pragma unroll
        for (int mt = 0; mt < 4; mt++) {
            size_t o = (size_t)(rowBase + mt*16 + ln) * 1024 + kk + quad*8;
            ah[mt] = *(const short8*)(Ah + o);
            al[mt] = *(const short8*)(Al + o);
        }
#pragma unroll
        for (int nt = 0; nt < 4; nt++) {
            size_t o = (size_t)(colBase + nt*16 + ln) * 1024 + kk + quad*8;
            bh[nt] = *(const short8*)(Wh + o);
            bl[nt] = *(const short8*)(Wl + o);
        }
#pragma unroll
        for (int mt = 0; mt < 4; mt++)
#pragma unroll
            for (int nt = 0; nt < 4; nt++) {
                acc[mt][nt] = MFMA(ah[mt], bh[nt], acc[mt][nt]);
                acc[mt][nt] = MFMA(ah[mt], bl[nt], acc[mt][nt]);
                acc[mt][nt] = MFMA(al[mt], bh[nt], acc[mt][nt]);
            }
    }

#pragma unroll
    for (int mt = 0; mt < 4; mt++) {
#pragma unroll
        for (int nt = 0; nt < 4; nt++) {
            int col = colBase + nt*16 + ln;
            float bv = bias[col];
#pragma unroll
            for (int i = 0; i < 4; i++) {
                int row = rowBase + mt*16 + quad*4 + i;   // D: row=quad*4+reg, col=ln
                float val = (acc[mt][nt][i] + bv) * scale;
                int b_  = row >> 11, s = row & 2047;
                int h   = col >> 6,  d = col & 63;
                int bh_ = b_ * 16 + h;
                if (mode == 2) {
                    oh[((size_t)bh_ * 64 + d) * 2048 + s] = f2bf(val);
                } else {
                    size_t idx = ((size_t)bh_ * 2048 + s) * 64 + d;
                    unsigned short hv = f2bf(val);
                    oh[idx] = hv;
                    ol[idx] = f2bf(val - bf2f(hv));
                }
            }
        }
    }
}

// out = concat(bf16) @ Wo^T + bo  (split Wo, fp32 out). 128x128 body.
__global__ __launch_bounds__(256) void gemm_out(
    const short* __restrict__ A,
    const short* __restrict__ Wh, const short* __restrict__ Wl,
    const float* __restrict__ bias, float* __restrict__ out)
{
    int tid  = threadIdx.x;
    int w    = tid >> 6;
    int lane = tid & 63;
    int ln   = lane & 15;
    int quad = lane >> 4;
    int rowBase = blockIdx.y * 128 + (w & 1) * 64;
    int colBase = blockIdx.x * 128 + (w >> 1) * 64;

    f32x4 acc[4][4];
#pragma unroll
    for (int i = 0; i < 4; i++)
#pragma unroll
        for (int j = 0; j < 4; j++) acc[i][j] = (f32x4){0.f, 0.f, 0.f, 0.f};

    for (int kk = 0; kk < 1024; kk += 32) {
        short8 a[4], bh[4], bl[4];
#pragma unroll
        for (int mt = 0; mt < 4; mt++)
            a[mt] = *(const short8*)(A + (size_t)(rowBase + mt*16 + ln) * 1024 + kk + quad*8);
#pragma unroll
        for (int nt = 0; nt < 4; nt++) {
            size_t o = (size_t)(colBase + nt*16 + ln) * 1024 + kk + quad*8;
            bh[nt] = *(const short8*)(Wh + o);
            bl[nt] = *(const short8*)(Wl + o);
        }
#pragma unroll
        for (int mt = 0; mt < 4; mt++)
#pragma unroll
            for (int nt = 0; nt < 4; nt++) {
                acc[mt][nt] = MFMA(a[mt], bh[nt], acc[mt][nt]);
                acc[mt][nt] = MFMA(a[mt], bl[nt], acc[mt][nt]);
            }
    }

#pragma unroll
    for (int mt = 0; mt < 4; mt++) {
#pragma unroll
        for (int nt = 0; nt < 4; nt++) {
            int col = colBase + nt*16 + ln;
            float bv = bias[col];
#pragma unroll
            for (int i = 0; i < 4; i++) {
                int row = rowBase + mt*16 + quad*4 + i;
                out[(size_t)row * 1024 + col] = acc[mt][nt][i] + bv;
            }
        }
    }
}

// rowsum[q] += sum over this block's k-half of 2^(c_qk).  Split-precision.
// grid (16 qtiles, 2 ksplit, 32 bh) = 1024 blocks (4/CU).
__global__ __launch_bounds__(256) void attn_rowsum(
    const short* __restrict__ Qhi, const short* __restrict__ Qlo,
    const short* __restrict__ Khi, const short* __restrict__ Klo,
    float* __restrict__ rowsum)
{
    int bh = blockIdx.z, tid = threadIdx.x;
    int w = tid >> 6, lane = tid & 63, ln = lane & 15, quad = lane >> 4;
    int qb  = blockIdx.x * 128 + w * 32;
    int kt0 = blockIdx.y * 64;
    const short* QH = Qhi + (size_t)bh * 2048 * 64;
    const short* QL = Qlo + (size_t)bh * 2048 * 64;
    const short* KH = Khi + (size_t)bh * 2048 * 64;
    const short* KL = Klo + (size_t)bh * 2048 * 64;

    short8 qh[2][2], ql[2][2];
#pragma unroll
    for (int mt = 0; mt < 2; mt++)
#pragma unroll
        for (int half = 0; half < 2; half++) {
            size_t o = (size_t)(qb + mt*16 + ln) * 64 + half*32 + quad*8;
            qh[mt][half] = *(const short8*)(QH + o);
            ql[mt][half] = *(const short8*)(QL + o);
        }

    short8 kh[2][2], kl[2][2];   // [buf][dchunk]
    auto loadK = [&](int buf, int kt) {
        size_t ko = (size_t)(kt*16 + ln) * 64 + quad*8;
        kh[buf][0] = *(const short8*)(KH + ko);
        kh[buf][1] = *(const short8*)(KH + ko + 32);
        kl[buf][0] = *(const short8*)(KL + ko);
        kl[buf][1] = *(const short8*)(KL + ko + 32);
    };

    float racc[2][4] = {{0.f,0.f,0.f,0.f},{0.f,0.f,0.f,0.f}};
    auto comp = [&](int buf) {
#pragma unroll
        for (int mt = 0; mt < 2; mt++) {
            f32x4 c1 = (f32x4){0.f,0.f,0.f,0.f};
            f32x4 c2 = (f32x4){0.f,0.f,0.f,0.f};
            c1 = MFMA(qh[mt][0], kh[buf][0], c1); c1 = MFMA(qh[mt][1], kh[buf][1], c1);
            c2 = MFMA(qh[mt][0], kl[buf][0], c2); c2 = MFMA(qh[mt][1], kl[buf][1], c2);
            c2 = MFMA(ql[mt][0], kh[buf][0], c2); c2 = MFMA(ql[mt][1], kh[buf][1], c2);
#pragma unroll
            for (int i = 0; i < 4; i++)
                racc[mt][i] += PEXP(c1[i] + c2[i]);
        }
    };

    loadK(0, kt0);
    for (int t = 0; t < 64; t += 2) {
        loadK(1, kt0 + t + 1);
        comp(0);
        if (t + 2 < 64) loadK(0, kt0 + t + 2);
        comp(1);
    }
#pragma unroll
    for (int mt = 0; mt < 2; mt++)
#pragma unroll
        for (int i = 0; i < 4; i++)
            for (int d = 1; d < 16; d <<= 1)
                racc[mt][i] += __shfl_xor(racc[mt][i], d, 64);
    if (ln == 0) {
#pragma unroll
        for (int mt = 0; mt < 2; mt++)
#pragma unroll
            for (int i = 0; i < 4; i++)
                atomicAdd(&rowsum[bh * 2048 + qb + mt*16 + quad*4 + i], racc[mt][i]);
    }
}

// colsum[k] += sum over this block's q-half of 2^(c_qk) / rowsum[q].
// grid (16 ktiles, 2 qsplit, 32 bh) = 1024 blocks.
__global__ __launch_bounds__(256) void attn_colsum(
    const short* __restrict__ Qhi, const short* __restrict__ Qlo,
    const short* __restrict__ Khi, const short* __restrict__ Klo,
    const float* __restrict__ rowsum, float* __restrict__ colsum)
{
    __shared__ float sli[1024];
    int bh = blockIdx.z, tid = threadIdx.x;
    int q0 = blockIdx.y * 1024;
    for (int j = tid; j < 1024; j += 256)
        sli[j] = 1.0f / rowsum[bh * 2048 + q0 + j];
    __syncthreads();

    int w = tid >> 6, lane = tid & 63, ln = lane & 15, quad = lane >> 4;
    int kb = blockIdx.x * 128 + w * 32;
    const short* QH = Qhi + (size_t)bh * 2048 * 64;
    const short* QL = Qlo + (size_t)bh * 2048 * 64;
    const short* KH = Khi + (size_t)bh * 2048 * 64;
    const short* KL = Klo + (size_t)bh * 2048 * 64;

    short8 kh[2][2], kl[2][2];
#pragma unroll
    for (int nt = 0; nt < 2; nt++)
#pragma unroll
        for (int half = 0; half < 2; half++) {
            size_t o = (size_t)(kb + nt*16 + ln) * 64 + half*32 + quad*8;
            kh[nt][half] = *(const short8*)(KH + o);
            kl[nt][half] = *(const short8*)(KL + o);
        }

    short8 qh[2][2], ql[2][2];   // [buf][half]
    int qt0 = blockIdx.y * 64;   // 64 q-tiles of 16
    auto loadQ = [&](int buf, int qt) {
        size_t qo = (size_t)((qt0 + qt)*16 + ln) * 64 + quad*8;
        qh[buf][0] = *(const short8*)(QH + qo);
        qh[buf][1] = *(const short8*)(QH + qo + 32);
        ql[buf][0] = *(const short8*)(QL + qo);
        ql[buf][1] = *(const short8*)(QL + qo + 32);
    };

    float cacc[2] = {0.f, 0.f};
    auto comp = [&](int buf, int qt) {
#pragma unroll
        for (int nt = 0; nt < 2; nt++) {
            f32x4 c1 = (f32x4){0.f,0.f,0.f,0.f};
            f32x4 c2 = (f32x4){0.f,0.f,0.f,0.f};
            c1 = MFMA(qh[buf][0], kh[nt][0], c1); c1 = MFMA(qh[buf][1], kh[nt][1], c1);
            c2 = MFMA(qh[buf][0], kl[nt][0], c2); c2 = MFMA(qh[buf][1], kl[nt][1], c2);
            c2 = MFMA(ql[buf][0], kh[nt][0], c2); c2 = MFMA(ql[buf][1], kh[nt][1], c2);
#pragma unroll
            for (int i = 0; i < 4; i++) {
                int r = qt*16 + quad*4 + i;   // local within this q-half
                cacc[nt] += PEXP(c1[i] + c2[i]) * sli[r];
            }
        }
    };

    loadQ(0, 0);
    for (int qt = 0; qt < 64; qt += 2) {
        loadQ(1, qt + 1);
        comp(0, qt);
        if (qt + 2 < 64) loadQ(0, qt + 2);
        comp(1, qt + 1);
    }
#pragma unroll
    for (int nt = 0; nt < 2; nt++) {
        cacc[nt] += __shfl_xor(cacc[nt], 16, 64);
        cacc[nt] += __shfl_xor(cacc[nt], 32, 64);
        if (lane < 16) atomicAdd(&colsum[bh * 2048 + kb + nt*16 + lane], cacc[nt]);
    }
}

// Per (b,h): threshold = KEEP-th largest col_sum; mask = col_sum >= threshold.
__global__ __launch_bounds__(256) void topk_mask(
    const float* __restrict__ colsum, float* __restrict__ maskf)
{
    __shared__ unsigned keys[2048];
    __shared__ int cnt;
    int bh = blockIdx.x, tid = threadIdx.x;
    for (int j = tid; j < 2048; j += 256) {
        unsigned u = __float_as_uint(colsum[bh * 2048 + j]);
        keys[j] = (u & 0x80000000u) ? ~u : (u | 0x80000000u);
    }
    __syncthreads();
    unsigned long long lo = 0, hi = 0x100000000ULL;
    while (hi - lo > 1) {
        unsigned long long mid = (lo + hi) >> 1;
        if (tid == 0) cnt = 0;
        __syncthreads();
        int local = 0;
        for (int j = tid; j < 2048; j += 256) local += (keys[j] >= (unsigned)mid) ? 1 : 0;
        atomicAdd(&cnt, local);
        __syncthreads();
        int c = cnt;
        __syncthreads();
        if (c >= KEEP) lo = mid; else hi = mid;
    }
    unsigned thr = (unsigned)lo;
    for (int j = tid; j < 2048; j += 256)
        maskf[bh * 2048 + j] = (keys[j] >= thr) ? 1.0f : 0.0f;
}

// Vt[(bh*64+d)*2048+k] *= mask   (0/1 -> exact zeroing)
__global__ __launch_bounds__(256) void mask_v(
    unsigned short* __restrict__ Vt, const float* __restrict__ maskf)
{
    int i = blockIdx.x * 256 + threadIdx.x;   // short8 group
    int k8  = i & 255;
    int row = i >> 8;
    int bh  = row >> 6;
    const float* m = maskf + bh * 2048 + k8 * 8;
    short8 v = ((short8*)Vt)[i];
#pragma unroll
    for (int j = 0; j < 8; j++)
        if (m[j] == 0.0f) v[j] = 0;
    ((short8*)Vt)[i] = v;
}

// Flash-style PV, no block barriers (Pl per-wave LDS; in-order DS + fences).
// P = 2^c unnormalized; 1/rowsum applied in epilogue; V pre-masked.
__global__ __launch_bounds__(256) void attn_av(
    const short* __restrict__ Qhi, const short* __restrict__ Khi,
    const short* __restrict__ Vt, const float* __restrict__ rowsum,
    unsigned short* __restrict__ concat)
{
    __shared__ __align__(16) short Pl[4][2][16][40];   // [wave][mt][row][key+pad]
    int bh = blockIdx.y, tid = threadIdx.x;
    int w = tid >> 6, lane = tid & 63, ln = lane & 15, quad = lane >> 4;
    int qb = blockIdx.x * 128 + w * 32;
    const short* Q = Qhi + (size_t)bh * 2048 * 64;
    const short* K = Khi + (size_t)bh * 2048 * 64;
    const short* V = Vt  + (size_t)bh * 64 * 2048;

    short8 qh[2][2];
    float lrow[2][4];
#pragma unroll
    for (int mt = 0; mt < 2; mt++) {
#pragma unroll
        for (int half = 0; half < 2; half++)
            qh[mt][half] = *(const short8*)(Q + (size_t)(qb + mt*16 + ln) * 64 + half*32 + quad*8);
#pragma unroll
        for (int i = 0; i < 4; i++)
            lrow[mt][i] = 1.0f / rowsum[bh * 2048 + qb + mt*16 + quad*4 + i];
    }

    f32x4 o[2][4];
#pragma unroll
    for (int mt = 0; mt < 2; mt++)
#pragma unroll
        for (int nt = 0; nt < 4; nt++) o[mt][nt] = (f32x4){0.f,0.f,0.f,0.f};

    short8 kb_[2][2][2];   // [buf][half][part]
    short8 vb_[2][4];      // [buf][nt]
    auto loadKV = [&](int buf, int kc) {
#pragma unroll
        for (int half = 0; half < 2; half++) {
            size_t ko = (size_t)(kc*32 + half*16 + ln) * 64 + quad*8;
            kb_[buf][half][0] = *(const short8*)(K + ko);
            kb_[buf][half][1] = *(const short8*)(K + ko + 32);
        }
#pragma unroll
        for (int nt = 0; nt < 4; nt++)
            vb_[buf][nt] = *(const short8*)(V + (size_t)(nt*16 + ln) * 2048 + kc*32 + quad*8);
    };
    auto comp = [&](int buf) {
#pragma unroll
        for (int half = 0; half < 2; half++)
#pragma unroll
            for (int mt = 0; mt < 2; mt++) {
                f32x4 c = (f32x4){0.f,0.f,0.f,0.f};
                c = MFMA(qh[mt][0], kb_[buf][half][0], c);
                c = MFMA(qh[mt][1], kb_[buf][half][1], c);
#pragma unroll
                for (int i = 0; i < 4; i++)
                    Pl[w][mt][quad*4 + i][half*16 + ln] = (short)f2bf(PEXP(c[i]));
            }
        asm volatile("s_waitcnt lgkmcnt(0)" ::: "memory");
        short8 aP[2];
#pragma unroll
        for (int mt = 0; mt < 2; mt++)
            aP[mt] = *(const short8*)(&Pl[w][mt][ln][quad*8]);
#pragma unroll
        for (int nt = 0; nt < 4; nt++)
#pragma unroll
            for (int mt = 0; mt < 2; mt++)
                o[mt][nt] = MFMA(aP[mt], vb_[buf][nt], o[mt][nt]);
        asm volatile("" ::: "memory");
    };

    loadKV(0, 0);
    for (int kc = 0; kc < 64; kc += 2) {
        loadKV(1, kc + 1);
        comp(0);
        if (kc + 2 < 64) loadKV(0, kc + 2);
        comp(1);
    }

    int b_ = bh >> 4, h = bh & 15;
#pragma unroll
    for (int mt = 0; mt < 2; mt++)
#pragma unroll
        for (int nt = 0; nt < 4; nt++)
#pragma unroll
            for (int i = 0; i < 4; i++) {
                int qrow = qb + mt*16 + quad*4 + i;
                int col  = h*64 + nt*16 + ln;
                concat[((size_t)(b_*2048 + qrow)) * 1024 + col] =
                    f2bf(o[mt][nt][i] * lrow[mt][i]);
            }
}

extern "C" void kernel_launch(void* const* d_in, const int* in_sizes, int n_in,
                              void* d_out, int out_size, void* d_ws, size_t ws_size,
                              hipStream_t stream)
{
    const float* q  = (const float*)d_in[0];
    const float* k  = (const float*)d_in[1];
    const float* v  = (const float*)d_in[2];
    const float* Wq = (const float*)d_in[3];
    const float* bq = (const float*)d_in[4];
    const float* Wk = (const float*)d_in[5];
    const float* bk = (const float*)d_in[6];
    const float* Wv = (const float*)d_in[7];
    const float* bv = (const float*)d_in[8];
    const float* Wo = (const float*)d_in[9];
    const float* bo = (const float*)d_in[10];

    char* ws = (char*)d_ws;
    size_t off = 0;
    auto alloc = [&](size_t bytes) -> void* {
        void* p = ws + off;
        off += (bytes + 255) & ~(size_t)255;
        return p;
    };
    const size_t ASZ = (size_t)4096 * 1024 * 2;   // 8.4 MB bf16 activation
    const size_t WSZ = (size_t)1024 * 1024 * 2;   // 2 MB bf16 weight
    unsigned short* qh_ = (unsigned short*)alloc(ASZ);
    unsigned short* ql_ = (unsigned short*)alloc(ASZ);
    unsigned short* kh_ = (unsigned short*)alloc(ASZ);
    unsigned short* kl_ = (unsigned short*)alloc(ASZ);
    unsigned short* vh_ = (unsigned short*)alloc(ASZ);
    unsigned short* vl_ = (unsigned short*)alloc(ASZ);
    unsigned short* wqh = (unsigned short*)alloc(WSZ);
    unsigned short* wql = (unsigned short*)alloc(WSZ);
    unsigned short* wkh = (unsigned short*)alloc(WSZ);
    unsigned short* wkl = (unsigned short*)alloc(WSZ);
    unsigned short* wvh = (unsigned short*)alloc(WSZ);
    unsigned short* wvl = (unsigned short*)alloc(WSZ);
    unsigned short* woh = (unsigned short*)alloc(WSZ);
    unsigned short* wol = (unsigned short*)alloc(WSZ);
    short* Qhi = (short*)alloc(ASZ);
    short* Qlo = (short*)alloc(ASZ);
    short* Khi = (short*)alloc(ASZ);
    short* Klo = (short*)alloc(ASZ);
    short* Vt  = (short*)alloc(ASZ);
    float* rowsum = (float*)alloc((size_t)32 * 2048 * 4);   // rowsum+colsum adjacent
    float* colsum = (float*)alloc((size_t)32 * 2048 * 4);
    float* maskf  = (float*)alloc((size_t)32 * 2048 * 4);
    unsigned short* concat = (unsigned short*)alloc(ASZ);
    // total ~118 MB (same as round 5, known-safe)

    dim3 blk(256);
    const int An4 = 4096 * 1024 / 4, Wn4 = 1024 * 1024 / 4;

    cvt_split<<<An4/256, blk, 0, stream>>>(q,  qh_, ql_, An4);
    cvt_split<<<An4/256, blk, 0, stream>>>(k,  kh_, kl_, An4);
    cvt_split<<<An4/256, blk, 0, stream>>>(v,  vh_, vl_, An4);
    cvt_split<<<Wn4/256, blk, 0, stream>>>(Wq, wqh, wql, Wn4);
    cvt_split<<<Wn4/256, blk, 0, stream>>>(Wk, wkh, wkl, Wn4);
    cvt_split<<<Wn4/256, blk, 0, stream>>>(Wv, wvh, wvl, Wn4);
    cvt_split<<<Wn4/256, blk, 0, stream>>>(Wo, woh, wol, Wn4);
    zero_f32 <<<dim3(512), blk, 0, stream>>>(rowsum, 2 * 32 * 2048);  // rowsum+colsum

    gemm_qkv<<<dim3(8, 32, 3), blk, 0, stream>>>(
        (const short*)qh_, (const short*)ql_, (const short*)kh_, (const short*)kl_,
        (const short*)vh_, (const short*)vl_,
        (const short*)wqh, (const short*)wql, (const short*)wkh, (const short*)wkl,
        (const short*)wvh, (const short*)wvl,
        bq, bk, bv,
        (unsigned short*)Qhi, (unsigned short*)Qlo,
        (unsigned short*)Khi, (unsigned short*)Klo, (unsigned short*)Vt);

    attn_rowsum<<<dim3(16, 2, 32), blk, 0, stream>>>(Qhi, Qlo, Khi, Klo, rowsum);
    attn_colsum<<<dim3(16, 2, 32), blk, 0, stream>>>(Qhi, Qlo, Khi, Klo, rowsum, colsum);
    topk_mask  <<<dim3(32),   blk, 0, stream>>>(colsum, maskf);
    mask_v     <<<dim3(2048), blk, 0, stream>>>((unsigned short*)Vt, maskf);
    attn_av    <<<dim3(16, 32), blk, 0, stream>>>(Qhi, Khi, Vt, rowsum, concat);

    gemm_out<<<dim3(8, 32), blk, 0, stream>>>((const short*)concat,
        (const short*)woh, (const short*)wol, bo, (float*)d_out);
}

// Round 8
// 603.490 us; speedup vs baseline: 1.6675x; 1.4066x over previous
//
#include <hip/hip_runtime.h>

// ---------------------------------------------------------------------------
// Pruned multi-head attention. fp32 I/O, split-bf16 (hi+lo) MFMA compute.
// B=2, S=2048, D_MODEL=1024, H=16, d_k=64, keep=int(2048*0.9)=1843
//
// Round 8: GEMMs rebuilt m97-style — global_load_lds(16B) staging of all
// operand tiles into LDS (shared across the block's 4 waves), 2-barrier
// K-loop, ds_read_b128 fragments. R7's direct-register GEMM refetched each
// tile per-wave (FETCH_SIZE 203MB, MfmaUtil 12%). rowsum/colsum widened to
// 4 m-tiles/wave with 4-way k/q split (24 MFMA per 4 loads).
// ---------------------------------------------------------------------------

typedef __attribute__((ext_vector_type(8))) short short8;   // 8 bf16 (4 VGPRs)
typedef __attribute__((ext_vector_type(4))) short short4v;
typedef __attribute__((ext_vector_type(4))) float f32x4;

#define KEEP 1843

#if __has_builtin(__builtin_amdgcn_exp2f)
  #define PEXP(x) __builtin_amdgcn_exp2f(x)
  #define QSC 0.18033688011112042f   // log2(e)/8 folded into Q projection
#else
  #define PEXP(x) __expf(x)
  #define QSC 0.125f
#endif

#define AS1(p) ((const __attribute__((address_space(1))) void*)(p))
#define AS3(p) ((__attribute__((address_space(3))) void*)(p))

static __device__ __forceinline__ float bf2f(unsigned short s) {
    union { unsigned u; float f; } v; v.u = ((unsigned)s) << 16; return v.f;
}
static __device__ __forceinline__ unsigned short f2bf(float f) {
    union { float f; unsigned u; } v; v.f = f;
    unsigned u = v.u;
    unsigned r = (u + 0x7FFFu + ((u >> 16) & 1u)) >> 16;   // RNE
    return (unsigned short)r;
}

#define MFMA(A, B, C) __builtin_amdgcn_mfma_f32_16x16x32_bf16(A, B, C, 0, 0, 0)

// fp32 array -> hi/lo bf16 arrays (x = hi + lo to ~2^-17 relative)
__global__ __launch_bounds__(256) void cvt_split(
    const float* __restrict__ in, unsigned short* __restrict__ hi,
    unsigned short* __restrict__ lo, int n4)
{
    int i = blockIdx.x * 256 + threadIdx.x;
    if (i >= n4) return;
    f32x4 x = ((const f32x4*)in)[i];
    short4v h, l;
#pragma unroll
    for (int j = 0; j < 4; j++) {
        unsigned short hv = f2bf(x[j]);
        h[j] = (short)hv;
        l[j] = (short)f2bf(x[j] - bf2f(hv));
    }
    ((short4v*)hi)[i] = h;
    ((short4v*)lo)[i] = l;
}

__global__ __launch_bounds__(256) void zero_f32(float* __restrict__ p, int n) {
    int i = blockIdx.x * 256 + threadIdx.x;
    if (i < n) p[i] = 0.f;
}

// Fused Q/K/V projections, m97-style LDS staging. 128x128 tile, BK=32.
// z=0: Q -> bf16 hi+lo head layout, scaled QSC; z=1: K likewise; z=2: V -> V^T.
__global__ __launch_bounds__(256) void gemm_qkv(
    const short* __restrict__ A0, const short* __restrict__ Al0,
    const short* __restrict__ A1, const short* __restrict__ Al1,
    const short* __restrict__ A2, const short* __restrict__ Al2,
    const short* __restrict__ W0, const short* __restrict__ Wl0,
    const short* __restrict__ W1, const short* __restrict__ Wl1,
    const short* __restrict__ W2, const short* __restrict__ Wl2,
    const float* __restrict__ b0, const float* __restrict__ b1,
    const float* __restrict__ b2,
    unsigned short* __restrict__ Qhi, unsigned short* __restrict__ Qlo,
    unsigned short* __restrict__ Khi, unsigned short* __restrict__ Klo,
    unsigned short* __restrict__ Vt)
{
    int z = blockIdx.z;
    const short *Ahg, *Alg, *Whg, *Wlg; const float* bias;
    unsigned short *oh = 0, *ol = 0; float scale; int mode;
    if (z == 0)      { Ahg=A0; Alg=Al0; Whg=W0; Wlg=Wl0; bias=b0; oh=Qhi; ol=Qlo; scale=QSC;  mode=0; }
    else if (z == 1) { Ahg=A1; Alg=Al1; Whg=W1; Wlg=Wl1; bias=b1; oh=Khi; ol=Klo; scale=1.0f; mode=0; }
    else             { Ahg=A2; Alg=Al2; Whg=W2; Wlg=Wl2; bias=b2; oh=Vt;          scale=1.0f; mode=2; }

    __shared__ __align__(16) short Ah_l[128*32];
    __shared__ __align__(16) short Al_l[128*32];
    __shared__ __align__(16) short Wh_l[128*32];
    __shared__ __align__(16) short Wl_l[128*32];

    int tid  = threadIdx.x;
    int w    = tid >> 6;
    int lane = tid & 63;
    int ln   = lane & 15;
    int quad = lane >> 4;
    int rowBase = blockIdx.y * 128;
    int colBase = blockIdx.x * 128;
    int mBase = (w & 1) * 64;        // wave's quadrant inside 128x128
    int nBase = (w >> 1) * 64;

    // staging: wave w covers rows [w*32, w*32+32); lane -> row w*32+j*16+lane/4,
    // col (lane&3)*8; LDS dest = base + lane*16B (row-major [128][32]).
    int srow = (lane >> 2);
    int scol = (lane & 3) * 8;
    const short* Ag_h = Ahg + (size_t)rowBase * 1024;
    const short* Ag_l = Alg + (size_t)rowBase * 1024;
    const short* Wg_h = Whg + (size_t)colBase * 1024;
    const short* Wg_l = Wlg + (size_t)colBase * 1024;

    f32x4 acc[4][4];
#pragma unroll
    for (int i = 0; i < 4; i++)
#pragma unroll
        for (int j = 0; j < 4; j++) acc[i][j] = (f32x4){0.f, 0.f, 0.f, 0.f};

    for (int kk = 0; kk < 1024; kk += 32) {
#pragma unroll
        for (int j = 0; j < 2; j++) {
            int r = w*32 + j*16;
            size_t go = (size_t)(r + srow) * 1024 + kk + scol;
            __builtin_amdgcn_global_load_lds(AS1(Ag_h + go), AS3(Ah_l + r*32), 16, 0, 0);
            __builtin_amdgcn_global_load_lds(AS1(Ag_l + go), AS3(Al_l + r*32), 16, 0, 0);
            __builtin_amdgcn_global_load_lds(AS1(Wg_h + go), AS3(Wh_l + r*32), 16, 0, 0);
            __builtin_amdgcn_global_load_lds(AS1(Wg_l + go), AS3(Wl_l + r*32), 16, 0, 0);
        }
        __syncthreads();

        short8 ah[4], al[4], bh[4], bl[4];
#pragma unroll
        for (int mt = 0; mt < 4; mt++) {
            int r = mBase + mt*16 + ln;
            ah[mt] = *(const short8*)(Ah_l + r*32 + quad*8);
            al[mt] = *(const short8*)(Al_l + r*32 + quad*8);
        }
#pragma unroll
        for (int nt = 0; nt < 4; nt++) {
            int c = nBase + nt*16 + ln;
            bh[nt] = *(const short8*)(Wh_l + c*32 + quad*8);
            bl[nt] = *(const short8*)(Wl_l + c*32 + quad*8);
        }
#pragma unroll
        for (int mt = 0; mt < 4; mt++)
#pragma unroll
            for (int nt = 0; nt < 4; nt++) {
                acc[mt][nt] = MFMA(ah[mt], bh[nt], acc[mt][nt]);
                acc[mt][nt] = MFMA(ah[mt], bl[nt], acc[mt][nt]);
                acc[mt][nt] = MFMA(al[mt], bh[nt], acc[mt][nt]);
            }
        __syncthreads();
    }

#pragma unroll
    for (int mt = 0; mt < 4; mt++) {
#pragma unroll
        for (int nt = 0; nt < 4; nt++) {
            int col = colBase + nBase + nt*16 + ln;
            float bv = bias[col];
#pragma unroll
            for (int i = 0; i < 4; i++) {
                int row = rowBase + mBase + mt*16 + quad*4 + i;   // D: row=quad*4+reg
                float val = (acc[mt][nt][i] + bv) * scale;
                int b_  = row >> 11, s = row & 2047;
                int h   = col >> 6,  d = col & 63;
                int bh_ = b_ * 16 + h;
                if (mode == 2) {
                    oh[((size_t)bh_ * 64 + d) * 2048 + s] = f2bf(val);
                } else {
                    size_t idx = ((size_t)bh_ * 2048 + s) * 64 + d;
                    unsigned short hv = f2bf(val);
                    oh[idx] = hv;
                    ol[idx] = f2bf(val - bf2f(hv));
                }
            }
        }
    }
}

// out = concat(bf16) @ Wo^T + bo (split Wo, fp32 out), LDS-staged.
__global__ __launch_bounds__(256) void gemm_out(
    const short* __restrict__ Ag, const short* __restrict__ Whg,
    const short* __restrict__ Wlg, const float* __restrict__ bias,
    float* __restrict__ out)
{
    __shared__ __align__(16) short A_l[128*32];
    __shared__ __align__(16) short Wh_l[128*32];
    __shared__ __align__(16) short Wl_l[128*32];

    int tid  = threadIdx.x;
    int w    = tid >> 6;
    int lane = tid & 63;
    int ln   = lane & 15;
    int quad = lane >> 4;
    int rowBase = blockIdx.y * 128;
    int colBase = blockIdx.x * 128;
    int mBase = (w & 1) * 64;
    int nBase = (w >> 1) * 64;

    int srow = (lane >> 2);
    int scol = (lane & 3) * 8;
    const short* Abase = Ag  + (size_t)rowBase * 1024;
    const short* Whb   = Whg + (size_t)colBase * 1024;
    const short* Wlb   = Wlg + (size_t)colBase * 1024;

    f32x4 acc[4][4];
#pragma unroll
    for (int i = 0; i < 4; i++)
#pragma unroll
        for (int j = 0; j < 4; j++) acc[i][j] = (f32x4){0.f, 0.f, 0.f, 0.f};

    for (int kk = 0; kk < 1024; kk += 32) {
#pragma unroll
        for (int j = 0; j < 2; j++) {
            int r = w*32 + j*16;
            size_t go = (size_t)(r + srow) * 1024 + kk + scol;
            __builtin_amdgcn_global_load_lds(AS1(Abase + go), AS3(A_l  + r*32), 16, 0, 0);
            __builtin_amdgcn_global_load_lds(AS1(Whb   + go), AS3(Wh_l + r*32), 16, 0, 0);
            __builtin_amdgcn_global_load_lds(AS1(Wlb   + go), AS3(Wl_l + r*32), 16, 0, 0);
        }
        __syncthreads();

        short8 a[4], bh[4], bl[4];
#pragma unroll
        for (int mt = 0; mt < 4; mt++)
            a[mt] = *(const short8*)(A_l + (mBase + mt*16 + ln)*32 + quad*8);
#pragma unroll
        for (int nt = 0; nt < 4; nt++) {
            int c = nBase + nt*16 + ln;
            bh[nt] = *(const short8*)(Wh_l + c*32 + quad*8);
            bl[nt] = *(const short8*)(Wl_l + c*32 + quad*8);
        }
#pragma unroll
        for (int mt = 0; mt < 4; mt++)
#pragma unroll
            for (int nt = 0; nt < 4; nt++) {
                acc[mt][nt] = MFMA(a[mt], bh[nt], acc[mt][nt]);
                acc[mt][nt] = MFMA(a[mt], bl[nt], acc[mt][nt]);
            }
        __syncthreads();
    }

#pragma unroll
    for (int mt = 0; mt < 4; mt++) {
#pragma unroll
        for (int nt = 0; nt < 4; nt++) {
            int col = colBase + nBase + nt*16 + ln;
            float bv = bias[col];
#pragma unroll
            for (int i = 0; i < 4; i++) {
                int row = rowBase + mBase + mt*16 + quad*4 + i;
                out[(size_t)row * 1024 + col] = acc[mt][nt][i] + bv;
            }
        }
    }
}

// rowsum[q] += sum over this block's k-quarter of 2^(c_qk).  Split-precision.
// Wave owns 64 q rows (4 m-tiles). grid (8 qblocks, 4 ksplit, 32 bh).
__global__ __launch_bounds__(256) void attn_rowsum(
    const short* __restrict__ Qhi, const short* __restrict__ Qlo,
    const short* __restrict__ Khi, const short* __restrict__ Klo,
    float* __restrict__ rowsum)
{
    int bh = blockIdx.z, tid = threadIdx.x;
    int w = tid >> 6, lane = tid & 63, ln = lane & 15, quad = lane >> 4;
    int qb  = blockIdx.x * 256 + w * 64;
    int kt0 = blockIdx.y * 32;            // 32 k-tiles of 16 = 512 keys
    const short* QH = Qhi + (size_t)bh * 2048 * 64;
    const short* QL = Qlo + (size_t)bh * 2048 * 64;
    const short* KH = Khi + (size_t)bh * 2048 * 64;
    const short* KL = Klo + (size_t)bh * 2048 * 64;

    short8 qh[4][2], ql[4][2];
#pragma unroll
    for (int mt = 0; mt < 4; mt++)
#pragma unroll
        for (int half = 0; half < 2; half++) {
            size_t o = (size_t)(qb + mt*16 + ln) * 64 + half*32 + quad*8;
            qh[mt][half] = *(const short8*)(QH + o);
            ql[mt][half] = *(const short8*)(QL + o);
        }

    short8 kh[2][2], kl[2][2];   // [buf][dchunk]
    auto loadK = [&](int buf, int kt) {
        size_t ko = (size_t)(kt*16 + ln) * 64 + quad*8;
        kh[buf][0] = *(const short8*)(KH + ko);
        kh[buf][1] = *(const short8*)(KH + ko + 32);
        kl[buf][0] = *(const short8*)(KL + ko);
        kl[buf][1] = *(const short8*)(KL + ko + 32);
    };

    float racc[4][4] = {};
    auto comp = [&](int buf) {
#pragma unroll
        for (int mt = 0; mt < 4; mt++) {
            f32x4 c1 = (f32x4){0.f,0.f,0.f,0.f};
            f32x4 c2 = (f32x4){0.f,0.f,0.f,0.f};
            c1 = MFMA(qh[mt][0], kh[buf][0], c1); c1 = MFMA(qh[mt][1], kh[buf][1], c1);
            c2 = MFMA(qh[mt][0], kl[buf][0], c2); c2 = MFMA(qh[mt][1], kl[buf][1], c2);
            c2 = MFMA(ql[mt][0], kh[buf][0], c2); c2 = MFMA(ql[mt][1], kh[buf][1], c2);
#pragma unroll
            for (int i = 0; i < 4; i++)
                racc[mt][i] += PEXP(c1[i] + c2[i]);
        }
    };

    loadK(0, kt0);
    for (int t = 0; t < 32; t += 2) {
        loadK(1, kt0 + t + 1);
        comp(0);
        if (t + 2 < 32) loadK(0, kt0 + t + 2);
        comp(1);
    }
#pragma unroll
    for (int mt = 0; mt < 4; mt++)
#pragma unroll
        for (int i = 0; i < 4; i++)
            for (int d = 1; d < 16; d <<= 1)
                racc[mt][i] += __shfl_xor(racc[mt][i], d, 64);
    if (ln == 0) {
#pragma unroll
        for (int mt = 0; mt < 4; mt++)
#pragma unroll
            for (int i = 0; i < 4; i++)
                atomicAdd(&rowsum[bh * 2048 + qb + mt*16 + quad*4 + i], racc[mt][i]);
    }
}

// colsum[k] += sum over this block's q-quarter of 2^(c_qk)/rowsum[q].
// Wave owns 64 keys (4 n-tiles). grid (8 kblocks, 4 qsplit, 32 bh).
__global__ __launch_bounds__(256) void attn_colsum(
    const short* __restrict__ Qhi, const short* __restrict__ Qlo,
    const short* __restrict__ Khi, const short* __restrict__ Klo,
    const float* __restrict__ rowsum, float* __restrict__ colsum)
{
    __shared__ float sli[512];
    int bh = blockIdx.z, tid = threadIdx.x;
    int q0 = blockIdx.y * 512;
    for (int j = tid; j < 512; j += 256)
        sli[j] = 1.0f / rowsum[bh * 2048 + q0 + j];
    __syncthreads();

    int w = tid >> 6, lane = tid & 63, ln = lane & 15, quad = lane >> 4;
    int kb  = blockIdx.x * 256 + w * 64;
    int qt0 = blockIdx.y * 32;            // 32 q-tiles of 16
    const short* QH = Qhi + (size_t)bh * 2048 * 64;
    const short* QL = Qlo + (size_t)bh * 2048 * 64;
    const short* KH = Khi + (size_t)bh * 2048 * 64;
    const short* KL = Klo + (size_t)bh * 2048 * 64;

    short8 kh[4][2], kl[4][2];
#pragma unroll
    for (int nt = 0; nt < 4; nt++)
#pragma unroll
        for (int half = 0; half < 2; half++) {
            size_t o = (size_t)(kb + nt*16 + ln) * 64 + half*32 + quad*8;
            kh[nt][half] = *(const short8*)(KH + o);
            kl[nt][half] = *(const short8*)(KL + o);
        }

    short8 qh[2][2], ql[2][2];   // [buf][half]
    auto loadQ = [&](int buf, int qt) {
        size_t qo = (size_t)((qt0 + qt)*16 + ln) * 64 + quad*8;
        qh[buf][0] = *(const short8*)(QH + qo);
        qh[buf][1] = *(const short8*)(QH + qo + 32);
        ql[buf][0] = *(const short8*)(QL + qo);
        ql[buf][1] = *(const short8*)(QL + qo + 32);
    };

    float cacc[4] = {0.f, 0.f, 0.f, 0.f};
    auto comp = [&](int buf, int qt) {
#pragma unroll
        for (int nt = 0; nt < 4; nt++) {
            f32x4 c1 = (f32x4){0.f,0.f,0.f,0.f};
            f32x4 c2 = (f32x4){0.f,0.f,0.f,0.f};
            c1 = MFMA(qh[buf][0], kh[nt][0], c1); c1 = MFMA(qh[buf][1], kh[nt][1], c1);
            c2 = MFMA(qh[buf][0], kl[nt][0], c2); c2 = MFMA(qh[buf][1], kl[nt][1], c2);
            c2 = MFMA(ql[buf][0], kh[nt][0], c2); c2 = MFMA(ql[buf][1], kh[nt][1], c2);
#pragma unroll
            for (int i = 0; i < 4; i++) {
                int r = qt*16 + quad*4 + i;
                cacc[nt] += PEXP(c1[i] + c2[i]) * sli[r];
            }
        }
    };

    loadQ(0, 0);
    for (int qt = 0; qt < 32; qt += 2) {
        loadQ(1, qt + 1);
        comp(0, qt);
        if (qt + 2 < 32) loadQ(0, qt + 2);
        comp(1, qt + 1);
    }
#pragma unroll
    for (int nt = 0; nt < 4; nt++) {
        cacc[nt] += __shfl_xor(cacc[nt], 16, 64);
        cacc[nt] += __shfl_xor(cacc[nt], 32, 64);
        if (lane < 16) atomicAdd(&colsum[bh * 2048 + kb + nt*16 + lane], cacc[nt]);
    }
}

// Per (b,h): threshold = KEEP-th largest col_sum; mask = col_sum >= threshold.
__global__ __launch_bounds__(256) void topk_mask(
    const float* __restrict__ colsum, float* __restrict__ maskf)
{
    __shared__ unsigned keys[2048];
    __shared__ int cnt;
    int bh = blockIdx.x, tid = threadIdx.x;
    for (int j = tid; j < 2048; j += 256) {
        unsigned u = __float_as_uint(colsum[bh * 2048 + j]);
        keys[j] = (u & 0x80000000u) ? ~u : (u | 0x80000000u);
    }
    __syncthreads();
    unsigned long long lo = 0, hi = 0x100000000ULL;
    while (hi - lo > 1) {
        unsigned long long mid = (lo + hi) >> 1;
        if (tid == 0) cnt = 0;
        __syncthreads();
        int local = 0;
        for (int j = tid; j < 2048; j += 256) local += (keys[j] >= (unsigned)mid) ? 1 : 0;
        atomicAdd(&cnt, local);
        __syncthreads();
        int c = cnt;
        __syncthreads();
        if (c >= KEEP) lo = mid; else hi = mid;
    }
    unsigned thr = (unsigned)lo;
    for (int j = tid; j < 2048; j += 256)
        maskf[bh * 2048 + j] = (keys[j] >= thr) ? 1.0f : 0.0f;
}

// Vt[(bh*64+d)*2048+k] *= mask   (0/1 -> exact zeroing)
__global__ __launch_bounds__(256) void mask_v(
    unsigned short* __restrict__ Vt, const float* __restrict__ maskf)
{
    int i = blockIdx.x * 256 + threadIdx.x;   // short8 group
    int k8  = i & 255;
    int row = i >> 8;
    int bh  = row >> 6;
    const float* m = maskf + bh * 2048 + k8 * 8;
    short8 v = ((short8*)Vt)[i];
#pragma unroll
    for (int j = 0; j < 8; j++)
        if (m[j] == 0.0f) v[j] = 0;
    ((short8*)Vt)[i] = v;
}

// Flash-style PV, no block barriers (Pl per-wave LDS; in-order DS + fences).
// P = 2^c unnormalized; 1/rowsum applied in epilogue; V pre-masked.
__global__ __launch_bounds__(256) void attn_av(
    const short* __restrict__ Qhi, const short* __restrict__ Khi,
    const short* __restrict__ Vt, const float* __restrict__ rowsum,
    unsigned short* __restrict__ concat)
{
    __shared__ __align__(16) short Pl[4][2][16][40];   // [wave][mt][row][key+pad]
    int bh = blockIdx.y, tid = threadIdx.x;
    int w = tid >> 6, lane = tid & 63, ln = lane & 15, quad = lane >> 4;
    int qb = blockIdx.x * 128 + w * 32;
    const short* Q = Qhi + (size_t)bh * 2048 * 64;
    const short* K = Khi + (size_t)bh * 2048 * 64;
    const short* V = Vt  + (size_t)bh * 64 * 2048;

    short8 qh[2][2];
    float lrow[2][4];
#pragma unroll
    for (int mt = 0; mt < 2; mt++) {
#pragma unroll
        for (int half = 0; half < 2; half++)
            qh[mt][half] = *(const short8*)(Q + (size_t)(qb + mt*16 + ln) * 64 + half*32 + quad*8);
#pragma unroll
        for (int i = 0; i < 4; i++)
            lrow[mt][i] = 1.0f / rowsum[bh * 2048 + qb + mt*16 + quad*4 + i];
    }

    f32x4 o[2][4];
#pragma unroll
    for (int mt = 0; mt < 2; mt++)
#pragma unroll
        for (int nt = 0; nt < 4; nt++) o[mt][nt] = (f32x4){0.f,0.f,0.f,0.f};

    short8 kb_[2][2][2];   // [buf][half][part]
    short8 vb_[2][4];      // [buf][nt]
    auto loadKV = [&](int buf, int kc) {
#pragma unroll
        for (int half = 0; half < 2; half++) {
            size_t ko = (size_t)(kc*32 + half*16 + ln) * 64 + quad*8;
            kb_[buf][half][0] = *(const short8*)(K + ko);
            kb_[buf][half][1] = *(const short8*)(K + ko + 32);
        }
#pragma unroll
        for (int nt = 0; nt < 4; nt++)
            vb_[buf][nt] = *(const short8*)(V + (size_t)(nt*16 + ln) * 2048 + kc*32 + quad*8);
    };
    auto comp = [&](int buf) {
#pragma unroll
        for (int half = 0; half < 2; half++)
#pragma unroll
            for (int mt = 0; mt < 2; mt++) {
                f32x4 c = (f32x4){0.f,0.f,0.f,0.f};
                c = MFMA(qh[mt][0], kb_[buf][half][0], c);
                c = MFMA(qh[mt][1], kb_[buf][half][1], c);
#pragma unroll
                for (int i = 0; i < 4; i++)
                    Pl[w][mt][quad*4 + i][half*16 + ln] = (short)f2bf(PEXP(c[i]));
            }
        asm volatile("s_waitcnt lgkmcnt(0)" ::: "memory");
        short8 aP[2];
#pragma unroll
        for (int mt = 0; mt < 2; mt++)
            aP[mt] = *(const short8*)(&Pl[w][mt][ln][quad*8]);
#pragma unroll
        for (int nt = 0; nt < 4; nt++)
#pragma unroll
            for (int mt = 0; mt < 2; mt++)
                o[mt][nt] = MFMA(aP[mt], vb_[buf][nt], o[mt][nt]);
        asm volatile("" ::: "memory");
    };

    loadKV(0, 0);
    for (int kc = 0; kc < 64; kc += 2) {
        loadKV(1, kc + 1);
        comp(0);
        if (kc + 2 < 64) loadKV(0, kc + 2);
        comp(1);
    }

    int b_ = bh >> 4, h = bh & 15;
#pragma unroll
    for (int mt = 0; mt < 2; mt++)
#pragma unroll
        for (int nt = 0; nt < 4; nt++)
#pragma unroll
            for (int i = 0; i < 4; i++) {
                int qrow = qb + mt*16 + quad*4 + i;
                int col  = h*64 + nt*16 + ln;
                concat[((size_t)(b_*2048 + qrow)) * 1024 + col] =
                    f2bf(o[mt][nt][i] * lrow[mt][i]);
            }
}

extern "C" void kernel_launch(void* const* d_in, const int* in_sizes, int n_in,
                              void* d_out, int out_size, void* d_ws, size_t ws_size,
                              hipStream_t stream)
{
    const float* q  = (const float*)d_in[0];
    const float* k  = (const float*)d_in[1];
    const float* v  = (const float*)d_in[2];
    const float* Wq = (const float*)d_in[3];
    const float* bq = (const float*)d_in[4];
    const float* Wk = (const float*)d_in[5];
    const float* bk = (const float*)d_in[6];
    const float* Wv = (const float*)d_in[7];
    const float* bv = (const float*)d_in[8];
    const float* Wo = (const float*)d_in[9];
    const float* bo = (const float*)d_in[10];

    char* ws = (char*)d_ws;
    size_t off = 0;
    auto alloc = [&](size_t bytes) -> void* {
        void* p = ws + off;
        off += (bytes + 255) & ~(size_t)255;
        return p;
    };
    const size_t ASZ = (size_t)4096 * 1024 * 2;   // 8.4 MB bf16 activation
    const size_t WSZ = (size_t)1024 * 1024 * 2;   // 2 MB bf16 weight
    unsigned short* qh_ = (unsigned short*)alloc(ASZ);
    unsigned short* ql_ = (unsigned short*)alloc(ASZ);
    unsigned short* kh_ = (unsigned short*)alloc(ASZ);
    unsigned short* kl_ = (unsigned short*)alloc(ASZ);
    unsigned short* vh_ = (unsigned short*)alloc(ASZ);
    unsigned short* vl_ = (unsigned short*)alloc(ASZ);
    unsigned short* wqh = (unsigned short*)alloc(WSZ);
    unsigned short* wql = (unsigned short*)alloc(WSZ);
    unsigned short* wkh = (unsigned short*)alloc(WSZ);
    unsigned short* wkl = (unsigned short*)alloc(WSZ);
    unsigned short* wvh = (unsigned short*)alloc(WSZ);
    unsigned short* wvl = (unsigned short*)alloc(WSZ);
    unsigned short* woh = (unsigned short*)alloc(WSZ);
    unsigned short* wol = (unsigned short*)alloc(WSZ);
    short* Qhi = (short*)alloc(ASZ);
    short* Qlo = (short*)alloc(ASZ);
    short* Khi = (short*)alloc(ASZ);
    short* Klo = (short*)alloc(ASZ);
    short* Vt  = (short*)alloc(ASZ);
    float* rowsum = (float*)alloc((size_t)32 * 2048 * 4);
    float* colsum = (float*)alloc((size_t)32 * 2048 * 4);
    float* maskf  = (float*)alloc((size_t)32 * 2048 * 4);
    unsigned short* concat = (unsigned short*)alloc(ASZ);
    // total ~118 MB (known-safe)

    dim3 blk(256);
    const int An4 = 4096 * 1024 / 4, Wn4 = 1024 * 1024 / 4;

    cvt_split<<<An4/256, blk, 0, stream>>>(q,  qh_, ql_, An4);
    cvt_split<<<An4/256, blk, 0, stream>>>(k,  kh_, kl_, An4);
    cvt_split<<<An4/256, blk, 0, stream>>>(v,  vh_, vl_, An4);
    cvt_split<<<Wn4/256, blk, 0, stream>>>(Wq, wqh, wql, Wn4);
    cvt_split<<<Wn4/256, blk, 0, stream>>>(Wk, wkh, wkl, Wn4);
    cvt_split<<<Wn4/256, blk, 0, stream>>>(Wv, wvh, wvl, Wn4);
    cvt_split<<<Wn4/256, blk, 0, stream>>>(Wo, woh, wol, Wn4);
    zero_f32 <<<dim3(512), blk, 0, stream>>>(rowsum, 2 * 32 * 2048);  // rowsum+colsum

    gemm_qkv<<<dim3(8, 32, 3), blk, 0, stream>>>(
        (const short*)qh_, (const short*)ql_, (const short*)kh_, (const short*)kl_,
        (const short*)vh_, (const short*)vl_,
        (const short*)wqh, (const short*)wql, (const short*)wkh, (const short*)wkl,
        (const short*)wvh, (const short*)wvl,
        bq, bk, bv,
        (unsigned short*)Qhi, (unsigned short*)Qlo,
        (unsigned short*)Khi, (unsigned short*)Klo, (unsigned short*)Vt);

    attn_rowsum<<<dim3(8, 4, 32), blk, 0, stream>>>(Qhi, Qlo, Khi, Klo, rowsum);
    attn_colsum<<<dim3(8, 4, 32), blk, 0, stream>>>(Qhi, Qlo, Khi, Klo, rowsum, colsum);
    topk_mask  <<<dim3(32),   blk, 0, stream>>>(colsum, maskf);
    mask_v     <<<dim3(2048), blk, 0, stream>>>((unsigned short*)Vt, maskf);
    attn_av    <<<dim3(16, 32), blk, 0, stream>>>(Qhi, Khi, Vt, rowsum, concat);

    gemm_out<<<dim3(8, 32), blk, 0, stream>>>((const short*)concat,
        (const short*)woh, (const short*)wol, bo, (float*)d_out);
}